// Round 9
// baseline (222.847 us; speedup 1.0000x reference)
//
#include <hip/hip_runtime.h>
#include <math.h>

#define B_   8
#define S_   1024
#define HDIM 768
#define FDIM 32
#define KDIM 800
#define D_   64
#define KSTEPS 25

constexpr float NEGV = -1000000000000.0f;

typedef __attribute__((ext_vector_type(8))) short short8;
typedef __attribute__((ext_vector_type(4))) float f32x4;

static __device__ __forceinline__ unsigned short f2bf(float f) {
    unsigned int x = __float_as_uint(f);
    unsigned int r = (x + 0x7fffu + ((x >> 16) & 1u)) >> 16;   // RNE
    return (unsigned short)r;
}
static __device__ __forceinline__ unsigned int pack2(float a, float b) {
    return (unsigned int)f2bf(a) | ((unsigned int)f2bf(b) << 16);
}

// ---------------------------------------------------------------------------
// k0: blocks 0..24: repack W1/W2 -> Wt bf16 (MFMA-frag chunk order) + bv.
//     blocks 25..32: rope table. (byte-identical R8)
// ---------------------------------------------------------------------------
__global__ __launch_bounds__(256) void k0_prep(
    const float* __restrict__ W1, const float* __restrict__ b1,
    const float* __restrict__ W2, const float* __restrict__ b2,
    unsigned short* __restrict__ Wt, float* __restrict__ bv,
    float2* __restrict__ rope)
{
    const int tid = threadIdx.x;
    if (blockIdx.x >= 25) {
        int e = (blockIdx.x - 25) * 256 + tid;
#pragma unroll
        for (int t = 0; t < 16; ++t, e += 2048) {
            const int s = e >> 5, i = e & 31;
            const float freq = exp2f(-(float)i * 0.4152410119f);
            float sv, cv;
            sincosf((float)s * freq, &sv, &cv);
            rope[e] = make_float2(cv, sv);
        }
        return;
    }

    __shared__ float shW[32][136];
    __shared__ float shW2[32][20];
    const int k0 = blockIdx.x << 5;
#pragma unroll
    for (int p = 0; p < 4; ++p) {
        const int flat = tid + (p << 8);
        const int kk = flat >> 5;
        const int c4 = (flat & 31) << 2;
        const float4 v = *(const float4*)(W1 + (size_t)(k0 + kk) * 128 + c4);
        shW[kk][c4 + 0] = v.x; shW[kk][c4 + 1] = v.y;
        shW[kk][c4 + 2] = v.z; shW[kk][c4 + 3] = v.w;
    }
    for (int i = tid; i < 576; i += 256)
        shW2[i / 18][i % 18] = W2[(size_t)k0 * 18 + i];
    __syncthreads();

    for (int i = tid; i < 768; i += 256) {
        const int tile = i >> 6, g = (i >> 4) & 3, col = i & 15;
        const int nc = tile * 16 + col;
        unsigned int pk[4];
#pragma unroll
        for (int h = 0; h < 4; ++h) {
            const int ka = g * 8 + 2 * h, kb = ka + 1;
            float a, b;
            if (nc < 64)       { a = shW[ka][2*nc];          b = shW[kb][2*nc]; }
            else if (nc < 128) { a = shW[ka][2*(nc-64)+1];   b = shW[kb][2*(nc-64)+1]; }
            else if (nc < 146) { a = shW2[ka][nc-128];       b = shW2[kb][nc-128]; }
            else               { a = 0.0f; b = 0.0f; }
            pk[h] = pack2(a, b);
        }
        *(uint4*)(Wt + ((size_t)blockIdx.x * 768 + i) * 8) =
            make_uint4(pk[0], pk[1], pk[2], pk[3]);
    }
    if (blockIdx.x == 0 && tid < 192) {
        float v = tid < 64  ? b1[2 * tid]
                : tid < 128 ? b1[2 * (tid - 64) + 1]
                : tid < 146 ? b2[tid - 128] : 0.0f;
        bv[tid] = v;
    }
}

// ---------------------------------------------------------------------------
// k1: fused h@[W1|W2] via MFMA + b + RoPE(table) -> qw/kw bf16 + bias_t.
// (byte-identical R8: 1 barrier/step, loads 2 steps ahead)
// ---------------------------------------------------------------------------
__global__ __launch_bounds__(256) void k1_proj(
    const float* __restrict__ lhs, const float* __restrict__ hf,
    const unsigned short* __restrict__ Wt, const float* __restrict__ bv,
    const float2* __restrict__ rope,
    unsigned short* __restrict__ qw, unsigned short* __restrict__ kw,
    float* __restrict__ bias_t)
{
    __shared__ __align__(16) unsigned short st[2][832 * 8];
    __shared__ __align__(16) unsigned short repack[16][128];

    const int tid  = threadIdx.x;
    const int m0   = blockIdx.x << 4;
    const int lane = tid & 63;
    const int w    = tid >> 6;
    const int r16  = lane & 15;
    const int g    = lane >> 4;

    const int arow   = tid >> 3;
    const int akq    = (tid & 7) << 2;
    const int achunk = ((akq >> 3) << 4) + arow;
    const int ahalf  = (akq >> 2) & 1;

    float4 rA;
    uint4  rB[3];

    auto loadA = [&](int c) {
        if (tid < 128) {
            const int k = (c << 5) + akq;
            rA = (k < HDIM)
               ? *(const float4*)(lhs + (size_t)(m0 + arow) * HDIM + k)
               : *(const float4*)(hf  + (size_t)(m0 + arow) * FDIM + (k - HDIM));
        }
    };
    auto loadB = [&](int c) {
#pragma unroll
        for (int u = 0; u < 3; ++u) {
            const int i = tid + (u << 8);
            rB[u] = *(const uint4*)(Wt + ((size_t)c * 768 + i) * 8);
        }
    };
    auto commit = [&](int buf) {
        if (tid < 128)
            *(uint2*)&st[buf][achunk * 8 + ahalf * 4] =
                make_uint2(pack2(rA.x, rA.y), pack2(rA.z, rA.w));
#pragma unroll
        for (int u = 0; u < 3; ++u) {
            const int i = tid + (u << 8);
            *(uint4*)&st[buf][(64 + i) * 8] = rB[u];
        }
    };

    f32x4 acc[3];
    const f32x4 zero = {0.0f, 0.0f, 0.0f, 0.0f};
#pragma unroll
    for (int u = 0; u < 3; ++u) acc[u] = zero;

    loadA(0); loadB(0); commit(0);
    loadA(1); loadB(1);

    for (int c = 0; c < KSTEPS; ++c) {
        __syncthreads();
        const int buf = c & 1;
        const short8 af = *(const short8*)&st[buf][(g * 16 + r16) * 8];
#pragma unroll
        for (int u = 0; u < 3; ++u) {
            const int tile = w * 3 + u;
            const short8 bf =
                *(const short8*)&st[buf][(64 + tile * 64 + g * 16 + r16) * 8];
            acc[u] = __builtin_amdgcn_mfma_f32_16x16x32_bf16(af, bf, acc[u], 0, 0, 0);
        }
        if (c + 1 < KSTEPS) {
            commit((c + 1) & 1);
            if (c + 2 < KSTEPS) { loadA(c + 2); loadB(c + 2); }
        }
    }

    const int bidx = m0 >> 10;
    const int s0   = m0 & (S_ - 1);
#pragma unroll
    for (int u = 0; u < 3; ++u) {
        const int tile = w * 3 + u;
        if (tile < 8) {
            const int jj  = (tile < 4 ? tile : tile - 4) * 16 + r16;
            const int fi  = jj >> 1;
            const float bvv = bv[tile * 16 + r16];
            const float sgn = (jj & 1) ? 1.0f : -1.0f;
            const float scl = (tile < 4) ? 0.125f : 1.0f;
            float x[4], p[4];
#pragma unroll
            for (int rr = 0; rr < 4; ++rr) x[rr] = acc[u][rr] + bvv;
#pragma unroll
            for (int rr = 0; rr < 4; ++rr) p[rr] = __shfl_xor(x[rr], 1, 64);
            const int cbase = (tile < 4 ? 0 : 64) + jj;
#pragma unroll
            for (int rr = 0; rr < 4; ++rr) {
                const float2 cs = rope[((s0 + g * 4 + rr) << 5) + fi];
                repack[g * 4 + rr][cbase] =
                    f2bf(fmaf(p[rr], sgn * cs.y, x[rr] * cs.x) * scl);
            }
        } else if (tile < 10) {
            const int cc = (tile - 8) * 16 + r16;
            if (cc < 18) {
                const float bvv = bv[tile * 16 + r16];
                f32x4 v;
#pragma unroll
                for (int rr = 0; rr < 4; ++rr) v[rr] = (acc[u][rr] + bvv) * 0.5f;
                *(f32x4*)(bias_t + (((size_t)(bidx * 18 + cc)) << 10) + s0 + g * 4) = v;
            }
        }
    }
    __syncthreads();
    {
        const int row = tid >> 4, seg = tid & 15;
        const uint4 v = *(const uint4*)&repack[row][seg * 8];
        if (seg < 8) *(uint4*)(qw + ((size_t)(m0 + row)) * D_ + seg * 8) = v;
        else         *(uint4*)(kw + ((size_t)(m0 + row)) * D_ + (seg - 8) * 8) = v;
    }
}

// ---------------------------------------------------------------------------
// k2: block = (b, t, 16 m-rows). Recomputes its 16x1024 QK^T strip via MFMA
// (kw panel L2-resident; recompute is ~free), LDS-transposes in two 8-row
// passes, and writes its 64KB output span FULLY CONTIGUOUS in address order.
// Consecutive blocks on an XCD cover consecutive 64KB spans (DRAM-friendly).
// ---------------------------------------------------------------------------
__global__ __launch_bounds__(256) void k2_logits(
    const unsigned short* __restrict__ qw, const unsigned short* __restrict__ kw,
    const float* __restrict__ bias_t, const int* __restrict__ mask,
    float* __restrict__ out)
{
    __shared__ __align__(16) unsigned short qsm[16 * 64];       // 2 KB
    __shared__ __align__(16) unsigned short ksm[2][64 * 64];    // 16 KB dbuf
    __shared__ __align__(16) float trbuf[8 * 1028];             // 32.9 KB
    __shared__ float mq[16], bmv[16];

    const int tid = threadIdx.x;
    const int i   = blockIdx.x;
    // swz = (i&7)*576 + (i>>3): XCD x owns batch x; within it, (t, m) with
    // m fastest -> sequential 64KB output spans in dispatch order.
    const int b   = i & 7;
    const int rem = i >> 3;          // 0..575 = t*64 + mc
    const int t   = rem >> 6;
    const int m0  = (rem & 63) << 4;

    // ---- stage q tile (16x64, XOR slot swizzle) + small vectors ----
    if (tid < 128) {
        const int row = tid >> 3, c8 = tid & 7;
        const uint4 v = *(const uint4*)(qw + ((size_t)(b << 10) + m0 + row) * D_ + (c8 << 3));
        *(uint4*)((char*)qsm + (row << 7) + ((c8 ^ (row & 7)) << 4)) = v;
    } else if (tid < 144) {
        mq[tid - 128] = (float)mask[(b << 10) + m0 + (tid - 128)];
    } else if (tid < 160) {
        bmv[tid - 144] = bias_t[((size_t)(b * 18 + 2 * t + 1) << 10) + m0 + (tid - 144)];
    }

    // per-thread column-constant epilogue operands (L2 reads, issued early)
    const int n4 = tid << 2;
    const f32x4 bn4 = *(const f32x4*)(bias_t + ((size_t)(b * 18 + 2 * t) << 10) + n4);
    const int4  mk4 = *(const int4*)(mask + (b << 10) + n4);
    const float fk[4] = {(float)mk4.x, (float)mk4.y, (float)mk4.z, (float)mk4.w};

    // ---- kw panel staging (64-row tiles, dbuf, 2-steps-ahead loads) ----
    uint4 rK[2];
    auto loadK = [&](int nt) {
#pragma unroll
        for (int u = 0; u < 2; ++u) {
            const int idx = tid + (u << 8);
            const int row = idx >> 3, c8 = idx & 7;
            rK[u] = *(const uint4*)(kw + ((size_t)(b << 10) + (nt << 6) + row) * D_ + (c8 << 3));
        }
    };
    auto commitK = [&](int buf) {
#pragma unroll
        for (int u = 0; u < 2; ++u) {
            const int idx = tid + (u << 8);
            const int row = idx >> 3, c8 = idx & 7;
            *(uint4*)((char*)ksm[buf] + (row << 7) + ((c8 ^ (row & 7)) << 4)) = rK[u];
        }
    };

    loadK(0); commitK(0); loadK(1);
    __syncthreads();                       // qsm + ksm[0] visible

    const int lane = tid & 63;
    const int w    = tid >> 6;
    const int r16  = lane & 15;
    const int g    = lane >> 4;

    // A-frags: constant across the nt loop
    short8 af[2];
#pragma unroll
    for (int ku = 0; ku < 2; ++ku) {
        const int slot = ((ku << 2) + g) ^ (r16 & 7);
        af[ku] = *(const short8*)((const char*)qsm + (r16 << 7) + (slot << 4));
    }

    f32x4 acc[16];
    const f32x4 zero = {0.0f, 0.0f, 0.0f, 0.0f};
#pragma unroll
    for (int nt = 0; nt < 16; ++nt) acc[nt] = zero;

#pragma unroll
    for (int nt = 0; nt < 16; ++nt) {
        if (nt) __syncthreads();           // ksm[nt&1] committed; prior reads done
        const int buf = nt & 1;
        const int row = (w << 4) + r16;    // wave w owns cols nt*64 + w*16 + r16
#pragma unroll
        for (int ku = 0; ku < 2; ++ku) {
            const int slot = ((ku << 2) + g) ^ (row & 7);
            const short8 bf = *(const short8*)((const char*)ksm[buf] + (row << 7) + (slot << 4));
            acc[nt] = __builtin_amdgcn_mfma_f32_16x16x32_bf16(af[ku], bf, acc[nt], 0, 0, 0);
        }
        if (nt + 1 < 16) {
            commitK((nt + 1) & 1);
            if (nt + 2 < 16) loadK(nt + 2);
        }
    }

    // ---- two 8-row transpose+store passes; stores sequential per row ----
    const size_t obase = (((size_t)(b * 9 + t)) << 20) + ((size_t)m0 << 10);
#pragma unroll
    for (int p = 0; p < 2; ++p) {
        __syncthreads();                   // p0: frag reads done; p1: p0 reads done
        if ((g >> 1) == p) {               // lanes holding rows 8p..8p+7
            const int rbase = (g & 1) << 2;
            const int colb  = (w << 4) + r16;
#pragma unroll
            for (int nt = 0; nt < 16; ++nt)
#pragma unroll
                for (int j = 0; j < 4; ++j)
                    trbuf[(rbase + j) * 1028 + (nt << 6) + colb] = acc[nt][j];
        }
        __syncthreads();
#pragma unroll
        for (int r = 0; r < 8; ++r) {
            const int mrow = (p << 3) + r;
            const int rg   = m0 + mrow;
            const float fm  = mq[mrow];
            const float bmr = bmv[mrow];
            const f32x4 a = *(const f32x4*)&trbuf[r * 1028 + n4];
            f32x4 v;
#pragma unroll
            for (int j = 0; j < 4; ++j) {
                const float pj = fm * fk[j];
                float ad = NEGV * ((1.0f - fm) * fk[j] + (1.0f - fk[j]));
                if (rg > n4 + j) ad += NEGV;
                const float accp = fmaf(a[j], pj, ad);
                v[j] = fmaf(bn4[j] + bmr, pj, accp);
            }
            *(f32x4*)(out + obase + ((size_t)mrow << 10) + n4) = v;
        }
    }
}

extern "C" void kernel_launch(void* const* d_in, const int* in_sizes, int n_in,
                              void* d_out, int out_size, void* d_ws, size_t ws_size,
                              hipStream_t stream) {
    const float* lhs  = (const float*)d_in[0];
    const float* hf   = (const float*)d_in[1];
    const int*   mask = (const int*)  d_in[2];
    const float* W1   = (const float*)d_in[3];
    const float* b1   = (const float*)d_in[4];
    const float* W2   = (const float*)d_in[5];
    const float* b2   = (const float*)d_in[6];
    float* out = (float*)d_out;

    unsigned short* qw = (unsigned short*)d_ws;              // 1 MB
    unsigned short* kw = qw + (size_t)B_ * S_ * D_;          // 1 MB
    float* bias_t = (float*)((char*)d_ws + (4u << 20));      // 576 KB @ 4 MB
    unsigned short* Wt = (unsigned short*)((char*)d_ws + (8u << 20)); // 300 KB
    float* bv = (float*)((char*)d_ws + (9u << 20));          // 768 B
    float2* rope = (float2*)((char*)d_ws + (10u << 20));     // 256 KB @ 10 MB

    k0_prep<<<33, 256, 0, stream>>>(W1, b1, W2, b2, Wt, bv, rope);
    k1_proj<<<(B_ * S_) / 16, 256, 0, stream>>>(lhs, hf, Wt, bv, rope,
                                                qw, kw, bias_t);
    k2_logits<<<B_ * 9 * 64, 256, 0, stream>>>(qw, kw, bias_t, mask, out);
}